// Round 8
// baseline (187047.473 us; speedup 1.0000x reference)
//
#include <hip/hip_runtime.h>
#include <stdint.h>

#define T_STEPS 8192
#define K_TAGS 1024
#define D_DIM 1024
#define START_TAG 1022
#define STOP_TAG 1023
#define NEGV (-10000.0f)
#define LOG2E 1.4426950408889634f
#define LN2 0.6931471805599453f
#define MARGIN2 40.0f   // lagged-shift slack (log2 units); r4/r6/r7-proven exact

#define NBLK 256      // blocks in persistent CRF kernel (r2's best geometry)
#define ROWS_PB 4     // one WAVE per row
#define TAG(u) ((unsigned)((u) >> 32))

// ---- agent-scope payload+tag atomics (serviced at MALL; L2-bypassing) ------
static __device__ __forceinline__ unsigned long long ld_agent_u64(
    const unsigned long long* p) {
  return __hip_atomic_load(p, __ATOMIC_RELAXED, __HIP_MEMORY_SCOPE_AGENT);
}
static __device__ __forceinline__ void st_agent_u64(unsigned long long* p,
                                                    unsigned long long v) {
  __hip_atomic_store(p, v, __ATOMIC_RELAXED, __HIP_MEMORY_SCOPE_AGENT);
}
static __device__ __forceinline__ unsigned ld_agent_u32(const unsigned* p) {
  return __hip_atomic_load(p, __ATOMIC_RELAXED, __HIP_MEMORY_SCOPE_AGENT);
}

// ---- wave64 DPP reductions (VALU-only) -------------------------------------
template <int CTRL>
static __device__ __forceinline__ float dpp_mov(float x, float old) {
  return __int_as_float(__builtin_amdgcn_update_dpp(
      __float_as_int(old), __float_as_int(x), CTRL, 0xF, 0xF, false));
}
static __device__ __forceinline__ float wave_red_max63(float x) {
  const float NI = -3.0e38f;
  x = fmaxf(x, dpp_mov<0x111>(x, NI));
  x = fmaxf(x, dpp_mov<0x112>(x, NI));
  x = fmaxf(x, dpp_mov<0x114>(x, NI));
  x = fmaxf(x, dpp_mov<0x118>(x, NI));
  x = fmaxf(x, dpp_mov<0x142>(x, NI));   // row_bcast:15
  x = fmaxf(x, dpp_mov<0x143>(x, NI));   // row_bcast:31
  return x;                              // lane 63 holds wave max
}
static __device__ __forceinline__ float wave_red_sum63(float x) {
  x += dpp_mov<0x111>(x, 0.0f);
  x += dpp_mov<0x112>(x, 0.0f);
  x += dpp_mov<0x114>(x, 0.0f);
  x += dpp_mov<0x118>(x, 0.0f);
  x += dpp_mov<0x142>(x, 0.0f);
  x += dpp_mov<0x143>(x, 0.0f);
  return x;                              // lane 63 holds wave sum
}

// ---- workspace init: s_0 (tag 1) in slot0, tag 0 in slot1, counters zeroed -
__global__ void init_ws_kernel(unsigned long long* fvbuf, unsigned* cnt,
                               int* bmax) {
  for (int i = blockIdx.x * blockDim.x + threadIdx.x; i <= T_STEPS;
       i += gridDim.x * blockDim.x) {
    cnt[i] = (i == 0) ? (unsigned)NBLK : 0u;   // cnt[t] = blocks at iter t
    if (i < K_TAGS) {
      float v = (i == START_TAG) ? 0.0f : NEGV * LOG2E;
      fvbuf[i] = (1ull << 32) | (unsigned long long)__float_as_uint(v);
      fvbuf[K_TAGS + i] = 0ull;
    }
  }
  if (blockIdx.x == 0 && threadIdx.x == 0) *bmax = 0;
}

// ---- gates: one wave per step t; t==T_STEPS computes the terminal gate -----
__global__ __launch_bounds__(256) void gate_kernel(
    const float* __restrict__ reps, const float* __restrict__ wc,
    const float* __restrict__ wu, const int* __restrict__ spk,
    float* __restrict__ gate, float* __restrict__ g_term) {
  const int gw = (int)((blockIdx.x * blockDim.x + threadIdx.x) >> 6);
  const int lane = threadIdx.x & 63;
  if (gw > T_STEPS) return;
  const int tcur = (gw < T_STEPS) ? gw : (T_STEPS - 1);
  const int tprv = (gw < T_STEPS) ? (gw > 0 ? gw - 1 : 0) : (T_STEPS - 1);
  const float* cur = reps + (size_t)tcur * D_DIM;
  const float* prv = reps + (size_t)tprv * D_DIM;
  float sc = 0.f, su = 0.f;
#pragma unroll
  for (int c = 0; c < 4; ++c) {
    const int d = lane * 4 + c * 256;
    float4 rp = *(const float4*)(prv + d);
    float4 rc = *(const float4*)(cur + d);
    float4 w1 = *(const float4*)(wc + d);
    float4 w2 = *(const float4*)(wc + D_DIM + d);
    float4 w3 = *(const float4*)(wu + d);
    float4 w4 = *(const float4*)(wu + D_DIM + d);
    sc += rp.x * w1.x + rp.y * w1.y + rp.z * w1.z + rp.w * w1.w;
    sc += rc.x * w2.x + rc.y * w2.y + rc.z * w2.z + rc.w * w2.w;
    su += rp.x * w3.x + rp.y * w3.y + rp.z * w3.z + rp.w * w3.w;
    su += rc.x * w4.x + rc.y * w4.y + rc.z * w4.z + rc.w * w4.w;
  }
#pragma unroll
  for (int off = 32; off; off >>= 1) {
    sc += __shfl_xor(sc, off);
    su += __shfl_xor(su, off);
  }
  if (lane == 0) {
    if (gw < T_STEPS) {
      bool uc = (gw > 0) && (spk[gw] != 0);
      float x = uc ? sc : su;
      gate[gw] = 1.0f / (1.0f + __expf(-x));
    } else {
      *g_term = 1.0f / (1.0f + __expf(-su));
    }
  }
}

// ---- global max over elementwise max(ti, ta) (for the lagged LSE shift) ----
__global__ __launch_bounds__(256) void bmax_kernel(
    const float* __restrict__ ti, const float* __restrict__ ta, int* bmax) {
  size_t i = (size_t)blockIdx.x * blockDim.x + threadIdx.x;
  size_t n = (size_t)K_TAGS * K_TAGS;
  float m = 0.f;  // clamped at 0 so int-compare atomicMax is valid
  for (size_t j = i; j < n; j += (size_t)gridDim.x * blockDim.x)
    m = fmaxf(m, fmaxf(ti[j], ta[j]));
#pragma unroll
  for (int off = 32; off; off >>= 1) m = fmaxf(m, __shfl_xor(m, off));
  if ((threadIdx.x & 63) == 0) atomicMax(bmax, __float_as_int(m));
}

// ---- persistent CRF forward scan: hybrid fast-path / counter-fallback ------
// 256 blocks x 256 threads (4 waves). Wave w of block b owns row r=4b+w.
// Per step: issue 4 tagged u64 loads (fast path). If any stale, the wave
// spins on ONE counter word (lane0 + shfl + s_sleep) then reloads once.
// Waiting traffic: 1 load/wave/round instead of 1024/block/round.
__global__ __launch_bounds__(256) void crf_kernel(
    const float* __restrict__ feats, const float* __restrict__ ti,
    const float* __restrict__ ta, const float* __restrict__ gate,
    const float* __restrict__ g_term_p, const int* __restrict__ bmax_p,
    unsigned long long* fvb, unsigned* cnt, float* __restrict__ out) {
  const int b = blockIdx.x;
  const int tid = threadIdx.x;
  const int lane = tid & 63;
  const int w = tid >> 6;             // wave id = local row
  const int r = b * ROWS_PB + w;      // this wave's global row
  const int e0 = tid * 4;             // four gathered entries per thread

  __shared__ __align__(16) float fvs[2][K_TAGS];
  __shared__ __align__(16) float wredM[2][4];  // slot-buffered lagged blockmax
  __shared__ float wredS[4];

  // register-resident, log2-scaled matrix slice for row r (16 cells/lane)
  float ta2[16], df2[16];
  {
    const float2* taP = reinterpret_cast<const float2*>(ta + (size_t)r * K_TAGS) + lane;
    const float2* tiP = reinterpret_cast<const float2*>(ti + (size_t)r * K_TAGS) + lane;
#pragma unroll
    for (int c = 0; c < 8; ++c) {
      float2 a = taP[64 * c];
      float2 i_ = tiP[64 * c];
      ta2[2 * c] = a.x * LOG2E;
      df2[2 * c] = (i_.x - a.x) * LOG2E;
      ta2[2 * c + 1] = a.y * LOG2E;
      df2[2 * c + 1] = (i_.y - a.y) * LOG2E;
    }
  }
  const float bmax2 = __int_as_float(*bmax_p) * LOG2E;

  // lagged-max buffers: max(fv_0) = 0 (START row), used at t=0
  if (tid < 8) wredM[tid >> 2][tid & 3] = 0.0f;
  // s_0 was published by init_ws_kernel (tag 1 in slot 0)

  float featv = (lane == 63) ? feats[r] : 0.0f;  // feats[0][r]

  for (int t = 0; t < T_STEPS; ++t) {
    const int slot = t & 1;
    const unsigned want = (unsigned)(t + 1);
    const float g = gate[t];  // uniform; overlaps the loads

    // 1) fast path: issue the 4 tagged loads once
    unsigned long long* ep = &fvb[slot * K_TAGS + e0];
    unsigned long long u0 = ld_agent_u64(ep + 0);
    unsigned long long u1 = ld_agent_u64(ep + 1);
    unsigned long long u2 = ld_agent_u64(ep + 2);
    unsigned long long u3 = ld_agent_u64(ep + 3);

    // counter add for this iteration (release: own store of s_t is covered;
    // its vmcnt(0) merges with the fast-path load wait -> ~free)
    if (tid == 0 && t > 0)
      __hip_atomic_fetch_add(&cnt[t], 1u, __ATOMIC_RELEASE,
                             __HIP_MEMORY_SCOPE_AGENT);

    bool stale = TAG(u0) < want || TAG(u1) < want || TAG(u2) < want ||
                 TAG(u3) < want;
    if (__any((int)stale)) {
      // 1b) fallback: wave spins on ONE counter word, low traffic
      unsigned c;
      do {
        c = (lane == 0) ? ld_agent_u32(&cnt[t]) : 0u;
        c = (unsigned)__shfl((int)c, 0);
        if (c < (unsigned)NBLK) __builtin_amdgcn_s_sleep(2);
      } while (c < (unsigned)NBLK);
      // reload; tag re-check is the actual correctness guarantee
      do {
        u0 = ld_agent_u64(ep + 0);
        u1 = ld_agent_u64(ep + 1);
        u2 = ld_agent_u64(ep + 2);
        u3 = ld_agent_u64(ep + 3);
      } while (TAG(u0) < want || TAG(u1) < want || TAG(u2) < want ||
               TAG(u3) < want);
    }
    const float v0 = __uint_as_float((unsigned)u0);
    const float v1 = __uint_as_float((unsigned)u1);
    const float v2 = __uint_as_float((unsigned)u2);
    const float v3 = __uint_as_float((unsigned)u3);

    // 2) stash -> one barrier
    *reinterpret_cast<float4*>(&fvs[slot][e0]) = make_float4(v0, v1, v2, v3);
    __syncthreads();

    // prefetch next step's emission; hides under compute
    float featv_next = 0.0f;
    if (lane == 63 && t + 1 < T_STEPS)
      featv_next = feats[(size_t)(t + 1) * K_TAGS + r];

    // 3) lagged shift: blockmax(fv_{t-1}) + bmax2 + margin (exact; r4-proven)
    const float4 mp = *reinterpret_cast<const float4*>(&wredM[slot ^ 1][0]);
    const float sh =
        fmaxf(fmaxf(mp.x, mp.y), fmaxf(mp.z, mp.w)) + bmax2 + MARGIN2;

    // 4) 16 cells/lane: acc += 2^(ta2 + g*df2 + fv - sh); conflict-free b64
    float a0 = 0.f, a1 = 0.f;
    const float2* fp = reinterpret_cast<const float2*>(&fvs[slot][0]) + lane;
#pragma unroll
    for (int c = 0; c < 8; ++c) {
      float2 f = fp[64 * c];
      a0 += exp2f(__builtin_fmaf(g, df2[2 * c], ta2[2 * c]) + (f.x - sh));
      a1 += exp2f(__builtin_fmaf(g, df2[2 * c + 1], ta2[2 * c + 1]) + (f.y - sh));
    }
    float acc = wave_red_sum63(a0 + a1);

    // 5) lane63 finalizes + publishes (tag t+2) into the other slot
    if (lane == 63) {
      float fvnew = sh + __log2f(acc) + featv * LOG2E;  // -inf if acc==0: OK
      st_agent_u64(&fvb[(slot ^ 1) * K_TAGS + r],
                   ((unsigned long long)(unsigned)(t + 2) << 32) |
                       (unsigned long long)__float_as_uint(fvnew));
    }

    // 6) off critical path: wave max of fv_t -> wredM[slot] for t+1
    float lm = wave_red_max63(fmaxf(fmaxf(v0, v1), fmaxf(v2, v3)));
    if (lane == 63) wredM[slot][w] = lm;

    featv = featv_next;
  }

  // ---- terminal LSE by block 0 ----------------------------------------------
  if (b == 0) {
    const unsigned want = (unsigned)(T_STEPS + 1);
    unsigned long long* ep = &fvb[(T_STEPS & 1) * K_TAGS + e0];
    unsigned long long u0 = ld_agent_u64(ep + 0);
    unsigned long long u1 = ld_agent_u64(ep + 1);
    unsigned long long u2 = ld_agent_u64(ep + 2);
    unsigned long long u3 = ld_agent_u64(ep + 3);
    while (TAG(u0) < want || TAG(u1) < want || TAG(u2) < want ||
           TAG(u3) < want) {
      u0 = ld_agent_u64(ep + 0);
      u1 = ld_agent_u64(ep + 1);
      u2 = ld_agent_u64(ep + 2);
      u3 = ld_agent_u64(ep + 3);
    }
    const float gt = *g_term_p;
    float term[4];
    const unsigned long long uu[4] = {u0, u1, u2, u3};
#pragma unroll
    for (int j = 0; j < 4; ++j) {
      const int k = e0 + j;
      float tis = ti[(size_t)STOP_TAG * K_TAGS + k];
      float tas = ta[(size_t)STOP_TAG * K_TAGS + k];
      term[j] = __uint_as_float((unsigned)uu[j]) +
                (tas + gt * (tis - tas)) * LOG2E;
    }
    float m = wave_red_max63(
        fmaxf(fmaxf(term[0], term[1]), fmaxf(term[2], term[3])));
    if (lane == 63) wredM[0][w] = m;
    __syncthreads();
    const float M2 = fmaxf(fmaxf(wredM[0][0], wredM[0][1]),
                           fmaxf(wredM[0][2], wredM[0][3]));
    float e = exp2f(term[0] - M2) + exp2f(term[1] - M2) +
              exp2f(term[2] - M2) + exp2f(term[3] - M2);
    e = wave_red_sum63(e);
    if (lane == 63) wredS[w] = e;
    __syncthreads();
    if (tid == 0) {
      float s = wredS[0] + wredS[1] + wredS[2] + wredS[3];
      out[0] = (M2 + __log2f(s)) * LN2;
    }
  }
}

extern "C" void kernel_launch(void* const* d_in, const int* in_sizes, int n_in,
                              void* d_out, int out_size, void* d_ws, size_t ws_size,
                              hipStream_t stream) {
  (void)in_sizes; (void)n_in; (void)out_size; (void)ws_size;
  const float* feats = (const float*)d_in[0];
  const float* reps  = (const float*)d_in[1];
  const float* wc    = (const float*)d_in[2];
  const float* wu    = (const float*)d_in[3];
  const float* ti    = (const float*)d_in[4];
  const float* ta    = (const float*)d_in[5];
  const int*   spk   = (const int*)d_in[6];
  float* out = (float*)d_out;

  // ws layout: fvbuf[2][1024] u64 (16 KiB) | gate[8192] f32 | g_term f32
  //            | bmax i32 | cnt[8193] u32
  unsigned long long* fvbuf = (unsigned long long*)d_ws;
  float* gate  = (float*)((char*)d_ws + 2 * K_TAGS * sizeof(unsigned long long));
  float* gterm = gate + T_STEPS;
  int*   bmax  = (int*)(gterm + 1);
  unsigned* cnt = (unsigned*)(bmax + 1);

  init_ws_kernel<<<dim3(34), dim3(256), 0, stream>>>(fvbuf, cnt, bmax);
  gate_kernel<<<dim3((T_STEPS + 1 + 3) / 4), dim3(256), 0, stream>>>(
      reps, wc, wu, spk, gate, gterm);
  bmax_kernel<<<dim3(512), dim3(256), 0, stream>>>(ti, ta, bmax);
  crf_kernel<<<dim3(NBLK), dim3(256), 0, stream>>>(feats, ti, ta, gate, gterm,
                                                   bmax, fvbuf, cnt, out);
}

// Round 9
// 76005.359 us; speedup vs baseline: 2.4610x; 2.4610x over previous
//
#include <hip/hip_runtime.h>
#include <stdint.h>

#define T_STEPS 8192
#define K_TAGS 1024
#define D_DIM 1024
#define START_TAG 1022
#define STOP_TAG 1023
#define NEGV (-10000.0f)
#define LOG2E 1.4426950408889634f
#define LN2 0.6931471805599453f
#define MARGIN2 40.0f   // lagged-shift slack (log2 units); r4/r6/r7-proven exact

#define NGRP 8        // one replica group per XCD (blockIdx % 8 heuristic)
#define BPG 32        // blocks per group
#define NBLK (NGRP * BPG)
#define ROWS_PB 32    // rows per block; half-wave (32 lanes) per row
#define NTHR 1024     // 16 waves
#define SPIN_LIMIT 4096  // poll iterations before sticky flip to MALL protocol

#define TAG(u) ((unsigned)((u) >> 32))

// ---- agent-scope (MALL) ops: the always-correct fallback path --------------
static __device__ __forceinline__ unsigned long long ld_agent_u64(
    const unsigned long long* p) {
  return __hip_atomic_load(p, __ATOMIC_RELAXED, __HIP_MEMORY_SCOPE_AGENT);
}
static __device__ __forceinline__ void st_agent_u64(unsigned long long* p,
                                                    unsigned long long v) {
  __hip_atomic_store(p, v, __ATOMIC_RELAXED, __HIP_MEMORY_SCOPE_AGENT);
}

// ---- XCD-local L2 ops: sc0 load bypasses L1, hits the shared XCD L2 --------
static __device__ __forceinline__ unsigned long long ld_l2_u64(
    const unsigned long long* p) {
  unsigned long long v;
  asm volatile("global_load_dwordx2 %0, %1, off sc0\n\ts_waitcnt vmcnt(0)"
               : "=v"(v)
               : "v"((unsigned long long)(uintptr_t)p)
               : "memory");
  return v;
}
static __device__ __forceinline__ void st_l2_u64(unsigned long long* p,
                                                 unsigned long long v) {
  // workgroup-scope relaxed store -> plain global_store, write-through to L2
  __hip_atomic_store(p, v, __ATOMIC_RELAXED, __HIP_MEMORY_SCOPE_WORKGROUP);
}
static __device__ __forceinline__ void wbl2_wait() {
#if __has_builtin(__builtin_amdgcn_buffer_wbl2)
  __builtin_amdgcn_buffer_wbl2();
#else
  asm volatile("buffer_wbl2" ::: "memory");
#endif
  asm volatile("s_waitcnt vmcnt(0)" ::: "memory");
}

// ---- poll one tagged entry; sticky timeout-flip L2 -> MALL ------------------
static __device__ __forceinline__ unsigned long long poll_one(
    unsigned long long* ep, unsigned want, bool& useL2, bool leader,
    unsigned long long* s0p, unsigned long long* s1p, unsigned long long pubA,
    unsigned long long pubB) {
  unsigned long long u = useL2 ? ld_l2_u64(ep) : ld_agent_u64(ep);
  if (TAG(u) >= want) return u;
  int spin = 0;
  for (;;) {
    u = useL2 ? ld_l2_u64(ep) : ld_agent_u64(ep);
    if (TAG(u) >= want) return u;
    if (useL2 && ++spin >= SPIN_LIMIT) {
      // L2 path broken (placement or semantics): flip permanently to MALL.
      useL2 = false;
      if (leader) {
        wbl2_wait();             // flush stale dirty lines (no resurrection)
        st_agent_u64(s0p, pubA); // re-publish latest state agent-scope
        st_agent_u64(s1p, pubB);
      }
    }
  }
}

// ---- wave64 DPP reductions (VALU-only) -------------------------------------
template <int CTRL>
static __device__ __forceinline__ float dpp_mov(float x, float old) {
  return __int_as_float(__builtin_amdgcn_update_dpp(
      __float_as_int(old), __float_as_int(x), CTRL, 0xF, 0xF, false));
}
static __device__ __forceinline__ float half_red_sum(float x) {
  x += dpp_mov<0x111>(x, 0.0f);
  x += dpp_mov<0x112>(x, 0.0f);
  x += dpp_mov<0x114>(x, 0.0f);
  x += dpp_mov<0x118>(x, 0.0f);
  x += dpp_mov<0x142>(x, 0.0f);   // row_bcast:15
  return x;                       // lanes 31/63 hold their half's total
}
static __device__ __forceinline__ float wave_red_max63(float x) {
  const float NI = -3.0e38f;
  x = fmaxf(x, dpp_mov<0x111>(x, NI));
  x = fmaxf(x, dpp_mov<0x112>(x, NI));
  x = fmaxf(x, dpp_mov<0x114>(x, NI));
  x = fmaxf(x, dpp_mov<0x118>(x, NI));
  x = fmaxf(x, dpp_mov<0x142>(x, NI));
  x = fmaxf(x, dpp_mov<0x143>(x, NI));  // row_bcast:31
  return x;                             // lane 63 holds wave max
}
static __device__ __forceinline__ float wave_red_sum63(float x) {
  x += dpp_mov<0x111>(x, 0.0f);
  x += dpp_mov<0x112>(x, 0.0f);
  x += dpp_mov<0x114>(x, 0.0f);
  x += dpp_mov<0x118>(x, 0.0f);
  x += dpp_mov<0x142>(x, 0.0f);
  x += dpp_mov<0x143>(x, 0.0f);
  return x;
}

// ---- workspace init: all 8 replica buffers, via MALL (authoritative) -------
__global__ void init_ws_kernel(unsigned long long* fvbuf, int* bmax) {
  int i = blockIdx.x * blockDim.x + threadIdx.x;
  if (i < NGRP * 2 * K_TAGS) {
    int e = i & (2 * K_TAGS - 1);
    int slot = e >> 10;
    int rr = e & (K_TAGS - 1);
    unsigned long long v;
    if (slot == 0) {
      float f = (rr == START_TAG) ? 0.0f : NEGV * LOG2E;
      v = (1ull << 32) | (unsigned long long)__float_as_uint(f);
    } else {
      v = 0ull;
    }
    st_agent_u64(&fvbuf[i], v);
  }
  if (i == 0) *bmax = 0;  // float 0.0 bits; true max is positive
}

// ---- gates: one wave per step t; t==T_STEPS computes the terminal gate -----
__global__ __launch_bounds__(256) void gate_kernel(
    const float* __restrict__ reps, const float* __restrict__ wc,
    const float* __restrict__ wu, const int* __restrict__ spk,
    float* __restrict__ gate, float* __restrict__ g_term) {
  const int gw = (int)((blockIdx.x * blockDim.x + threadIdx.x) >> 6);
  const int lane = threadIdx.x & 63;
  if (gw > T_STEPS) return;
  const int tcur = (gw < T_STEPS) ? gw : (T_STEPS - 1);
  const int tprv = (gw < T_STEPS) ? (gw > 0 ? gw - 1 : 0) : (T_STEPS - 1);
  const float* cur = reps + (size_t)tcur * D_DIM;
  const float* prv = reps + (size_t)tprv * D_DIM;
  float sc = 0.f, su = 0.f;
#pragma unroll
  for (int c = 0; c < 4; ++c) {
    const int d = lane * 4 + c * 256;
    float4 rp = *(const float4*)(prv + d);
    float4 rc = *(const float4*)(cur + d);
    float4 w1 = *(const float4*)(wc + d);
    float4 w2 = *(const float4*)(wc + D_DIM + d);
    float4 w3 = *(const float4*)(wu + d);
    float4 w4 = *(const float4*)(wu + D_DIM + d);
    sc += rp.x * w1.x + rp.y * w1.y + rp.z * w1.z + rp.w * w1.w;
    sc += rc.x * w2.x + rc.y * w2.y + rc.z * w2.z + rc.w * w2.w;
    su += rp.x * w3.x + rp.y * w3.y + rp.z * w3.z + rp.w * w3.w;
    su += rc.x * w4.x + rc.y * w4.y + rc.z * w4.z + rc.w * w4.w;
  }
#pragma unroll
  for (int off = 32; off; off >>= 1) {
    sc += __shfl_xor(sc, off);
    su += __shfl_xor(su, off);
  }
  if (lane == 0) {
    if (gw < T_STEPS) {
      bool uc = (gw > 0) && (spk[gw] != 0);
      float x = uc ? sc : su;
      gate[gw] = 1.0f / (1.0f + __expf(-x));
    } else {
      *g_term = 1.0f / (1.0f + __expf(-su));
    }
  }
}

// ---- global max over elementwise max(ti, ta) (for the lagged LSE shift) ----
__global__ __launch_bounds__(256) void bmax_kernel(
    const float* __restrict__ ti, const float* __restrict__ ta, int* bmax) {
  size_t i = (size_t)blockIdx.x * blockDim.x + threadIdx.x;
  size_t n = (size_t)K_TAGS * K_TAGS;
  float m = 0.f;  // clamped at 0 so int-compare atomicMax is valid
  for (size_t j = i; j < n; j += (size_t)gridDim.x * blockDim.x)
    m = fmaxf(m, fmaxf(ti[j], ta[j]));
#pragma unroll
  for (int off = 32; off; off >>= 1) m = fmaxf(m, __shfl_xor(m, off));
  if ((threadIdx.x & 63) == 0) atomicMax(bmax, __float_as_int(m));
}

// ---- persistent CRF forward scan: 8 XCD-local replica groups over L2 -------
// Group g = blockIdx%8 (round-robin -> one XCD, verified by timeout fallback).
// 32 blocks/group x 1024 threads; block rank owns rows [32*rank, 32*rank+32),
// half-wave per row, 32 cells/thread. Exchange: workgroup-scope stores +
// sc0 loads through the group's shared XCD L2 -- the MALL never sits on the
// per-step critical path. Every group redundantly computes the full scan.
__global__ __launch_bounds__(NTHR, 4) void crf_kernel(
    const float* __restrict__ feats, const float* __restrict__ ti,
    const float* __restrict__ ta, const float* __restrict__ gate,
    const float* __restrict__ g_term_p, const int* __restrict__ bmax_p,
    unsigned long long* fvbuf, float* __restrict__ out) {
  const int grp = blockIdx.x & (NGRP - 1);
  const int rank = blockIdx.x >> 3;
  const int tid = threadIdx.x;
  const int lane = tid & 63;
  const int w = tid >> 6;                 // wave id (0..15)
  const int j = lane & 31;                // team lane within half-wave
  const int h = lane >> 5;                // half id
  const int r = rank * ROWS_PB + 2 * w + h;  // this half-wave's row
  const bool leader = (j == 31);          // lanes 31 and 63

  unsigned long long* fvg = fvbuf + (size_t)grp * (2 * K_TAGS);
  unsigned long long* myS0 = &fvg[r];
  unsigned long long* myS1 = &fvg[K_TAGS + r];

  bool useL2 = true;  // sticky; flips to MALL protocol on poll timeout

  __shared__ __align__(16) float fvs[2][K_TAGS];
  __shared__ __align__(16) float wredM[2][16];  // slot-buffered lagged blockmax
  __shared__ float wredS[16];

  // register-resident, log2-scaled matrix slice: 32 cells for row r
  float ta2[32], df2[32];
  {
    const float2* taP = reinterpret_cast<const float2*>(ta + (size_t)r * K_TAGS) + j;
    const float2* tiP = reinterpret_cast<const float2*>(ti + (size_t)r * K_TAGS) + j;
#pragma unroll
    for (int c = 0; c < 16; ++c) {
      float2 a = taP[32 * c];
      float2 i_ = tiP[32 * c];
      ta2[2 * c] = a.x * LOG2E;
      df2[2 * c] = (i_.x - a.x) * LOG2E;
      ta2[2 * c + 1] = a.y * LOG2E;
      df2[2 * c + 1] = (i_.y - a.y) * LOG2E;
    }
  }
  const float bmax2 = __int_as_float(*bmax_p) * LOG2E;

  // leaders track their row's last published atoms (for fallback re-publish)
  unsigned long long pubA, pubB;
  {
    float f0 = (r == START_TAG) ? 0.0f : NEGV * LOG2E;
    pubA = (1ull << 32) | (unsigned long long)__float_as_uint(f0);
    pubB = 0ull;
  }

  // lagged-max buffers: max(fv_0) = 0 (START row), used at t=0
  if (tid < 32) wredM[tid >> 4][tid & 15] = 0.0f;
  // initial state published by init_ws_kernel (MALL authoritative; L2s are
  // clean at dispatch start, so first sc0 reads miss to MALL correctly)

  float featv = leader ? feats[r] : 0.0f;  // feats[0][r]

  for (int t = 0; t < T_STEPS; ++t) {
    const int slot = t & 1;
    const unsigned want = (unsigned)(t + 1);
    const float g = gate[t];  // uniform; overlaps the poll

    // 1) poll own tagged entry through the group's XCD L2 (or MALL if flipped)
    unsigned long long u = poll_one(&fvg[slot * K_TAGS + tid], want, useL2,
                                    leader, myS0, myS1, pubA, pubB);
    const float v = __uint_as_float((unsigned)u);

    // 2) stash -> one barrier
    fvs[slot][tid] = v;
    __syncthreads();

    // prefetch next step's emission; hides under compute
    float featv_next = 0.0f;
    if (leader && t + 1 < T_STEPS)
      featv_next = feats[(size_t)(t + 1) * K_TAGS + r];

    // 3) lagged shift: blockmax(fv_{t-1}) + bmax2 + margin (exact; r4-proven)
    const float4 mA = *reinterpret_cast<const float4*>(&wredM[slot ^ 1][0]);
    const float4 mB = *reinterpret_cast<const float4*>(&wredM[slot ^ 1][4]);
    const float4 mC = *reinterpret_cast<const float4*>(&wredM[slot ^ 1][8]);
    const float4 mD = *reinterpret_cast<const float4*>(&wredM[slot ^ 1][12]);
    float mm = fmaxf(fmaxf(fmaxf(mA.x, mA.y), fmaxf(mA.z, mA.w)),
                     fmaxf(fmaxf(mB.x, mB.y), fmaxf(mB.z, mB.w)));
    mm = fmaxf(mm, fmaxf(fmaxf(fmaxf(mC.x, mC.y), fmaxf(mC.z, mC.w)),
                         fmaxf(fmaxf(mD.x, mD.y), fmaxf(mD.z, mD.w))));
    const float sh = mm + bmax2 + MARGIN2;

    // 4) 32 cells: acc += 2^(ta2 + g*df2 + fv - sh)
    float a0 = 0.f, a1 = 0.f;
    const float2* fp = reinterpret_cast<const float2*>(&fvs[slot][0]) + j;
#pragma unroll
    for (int c = 0; c < 16; ++c) {
      float2 f = fp[32 * c];
      a0 += exp2f(__builtin_fmaf(g, df2[2 * c], ta2[2 * c]) + (f.x - sh));
      a1 += exp2f(__builtin_fmaf(g, df2[2 * c + 1], ta2[2 * c + 1]) + (f.y - sh));
    }
    float acc = half_red_sum(a0 + a1);  // lanes 31/63 hold row sums

    // 5) leaders publish (tag t+2) into the other slot via the active path
    if (leader) {
      float fvnew = sh + __log2f(acc) + featv * LOG2E;  // -inf if acc==0: OK
      unsigned long long newu =
          ((unsigned long long)(unsigned)(t + 2) << 32) |
          (unsigned long long)__float_as_uint(fvnew);
      unsigned long long* tp = (slot ^ 1) ? myS1 : myS0;
      if (useL2) st_l2_u64(tp, newu);
      else st_agent_u64(tp, newu);
      if (slot ^ 1) pubB = newu; else pubA = newu;
    }

    // 6) off critical path: wave max of polled fv_t -> wredM[slot] for t+1
    float lm = wave_red_max63(v);
    if (lane == 63) wredM[slot][w] = lm;

    featv = featv_next;
  }

  // ---- terminal LSE: rank 31 of EVERY group writes identical out[0] ---------
  if (rank == BPG - 1) {
    __syncthreads();  // all waves past their last wredM reads
    const unsigned want = (unsigned)(T_STEPS + 1);
    unsigned long long u = poll_one(&fvg[(T_STEPS & 1) * K_TAGS + tid], want,
                                    useL2, leader, myS0, myS1, pubA, pubB);
    const float gt = *g_term_p;
    const float tis = ti[(size_t)STOP_TAG * K_TAGS + tid];
    const float tas = ta[(size_t)STOP_TAG * K_TAGS + tid];
    const float term2 =
        __uint_as_float((unsigned)u) + (tas + gt * (tis - tas)) * LOG2E;

    float m = wave_red_max63(term2);
    if (lane == 63) wredM[0][w] = m;
    __syncthreads();
    float mm = wredM[0][0];
#pragma unroll
    for (int i = 1; i < 16; ++i) mm = fmaxf(mm, wredM[0][i]);
    float e = exp2f(term2 - mm);
    e = wave_red_sum63(e);
    if (lane == 63) wredS[w] = e;
    __syncthreads();
    if (tid == 0) {
      float s = 0.f;
#pragma unroll
      for (int i = 0; i < 16; ++i) s += wredS[i];
      out[0] = (mm + __log2f(s)) * LN2;  // identical across groups
    }
  }
}

extern "C" void kernel_launch(void* const* d_in, const int* in_sizes, int n_in,
                              void* d_out, int out_size, void* d_ws, size_t ws_size,
                              hipStream_t stream) {
  (void)in_sizes; (void)n_in; (void)out_size; (void)ws_size;
  const float* feats = (const float*)d_in[0];
  const float* reps  = (const float*)d_in[1];
  const float* wc    = (const float*)d_in[2];
  const float* wu    = (const float*)d_in[3];
  const float* ti    = (const float*)d_in[4];
  const float* ta    = (const float*)d_in[5];
  const int*   spk   = (const int*)d_in[6];
  float* out = (float*)d_out;

  // ws layout: fvbuf[8 groups][2][1024] u64 (128 KiB) | gate[8192] f32
  //            | g_term f32 | bmax i32
  unsigned long long* fvbuf = (unsigned long long*)d_ws;
  float* gate  = (float*)((char*)d_ws +
                          (size_t)NGRP * 2 * K_TAGS * sizeof(unsigned long long));
  float* gterm = gate + T_STEPS;
  int*   bmax  = (int*)(gterm + 1);

  init_ws_kernel<<<dim3(64), dim3(256), 0, stream>>>(fvbuf, bmax);
  gate_kernel<<<dim3((T_STEPS + 1 + 3) / 4), dim3(256), 0, stream>>>(
      reps, wc, wu, spk, gate, gterm);
  bmax_kernel<<<dim3(512), dim3(256), 0, stream>>>(ti, ta, bmax);
  crf_kernel<<<dim3(NBLK), dim3(NTHR), 0, stream>>>(feats, ti, ta, gate, gterm,
                                                    bmax, fvbuf, out);
}

// Round 10
// 46841.904 us; speedup vs baseline: 3.9932x; 1.6226x over previous
//
#include <hip/hip_runtime.h>
#include <stdint.h>

#define T_STEPS 8192
#define K_TAGS 1024
#define D_DIM 1024
#define START_TAG 1022
#define STOP_TAG 1023
#define NEGV (-10000.0f)
#define LOG2E 1.4426950408889634f
#define LN2 0.6931471805599453f
#define MARGIN2 40.0f   // lagged-shift slack (log2 units); r4/r6/r7/r9-proven exact

#define NGRP 8          // replica groups, keyed by HW XCC_ID
#define BPG 32          // worker blocks per group
#define NCAND 256       // candidate blocks launched (pigeonhole: >=1 viable group)
#define ROWS_PB 32      // rows per worker block; half-wave per row
#define NTHR 1024       // 16 waves
#define TIMEOUT_IT 16384  // poll iterations before raising the group flag

#define TAG(u) ((unsigned)((u) >> 32))

// ---- agent-scope (MALL) ops: always-correct fallback path ------------------
static __device__ __forceinline__ unsigned long long ld_agent_u64(
    const unsigned long long* p) {
  return __hip_atomic_load(p, __ATOMIC_RELAXED, __HIP_MEMORY_SCOPE_AGENT);
}
static __device__ __forceinline__ void st_agent_u64(unsigned long long* p,
                                                    unsigned long long v) {
  __hip_atomic_store(p, v, __ATOMIC_RELAXED, __HIP_MEMORY_SCOPE_AGENT);
}

// ---- XCD-local L2 ops: sc0 load bypasses L1, hits the shared XCD L2 --------
static __device__ __forceinline__ unsigned long long ld_l2_u64(
    const unsigned long long* p) {
  unsigned long long v;
  asm volatile("global_load_dwordx2 %0, %1, off sc0\n\ts_waitcnt vmcnt(0)"
               : "=v"(v)
               : "v"((unsigned long long)(uintptr_t)p)
               : "memory");
  return v;
}
static __device__ __forceinline__ void st_l2_u64(unsigned long long* p,
                                                 unsigned long long v) {
  // workgroup-scope relaxed store -> plain global_store (write-through to L2)
  __hip_atomic_store(p, v, __ATOMIC_RELAXED, __HIP_MEMORY_SCOPE_WORKGROUP);
}
static __device__ __forceinline__ void wbl2_wait() {
#if __has_builtin(__builtin_amdgcn_buffer_wbl2)
  __builtin_amdgcn_buffer_wbl2();
#else
  asm volatile("buffer_wbl2" ::: "memory");
#endif
  asm volatile("s_waitcnt vmcnt(0)" ::: "memory");
}

// ---- poll one tagged entry; group-coordinated sticky flip L2 -> MALL --------
static __device__ __forceinline__ unsigned long long poll_entry(
    unsigned long long* ep, unsigned want, bool& l2mode, unsigned* gflag,
    bool leader, unsigned long long* s0p, unsigned long long* s1p,
    unsigned long long pubA, unsigned long long pubB) {
  unsigned long long u = l2mode ? ld_l2_u64(ep) : ld_agent_u64(ep);
  if (TAG(u) >= want) return u;
  int it = 0;
  for (;;) {
    u = l2mode ? ld_l2_u64(ep) : ld_agent_u64(ep);
    if (TAG(u) >= want) return u;
    ++it;
    if (l2mode && (it & 1023) == 0) {
      bool bad;
      if (it >= TIMEOUT_IT) {
        __hip_atomic_store(gflag, 1u, __ATOMIC_RELAXED,
                           __HIP_MEMORY_SCOPE_AGENT);
        bad = true;
      } else {
        bad = __hip_atomic_load(gflag, __ATOMIC_RELAXED,
                                __HIP_MEMORY_SCOPE_AGENT) != 0;
      }
      if (bad) {
        l2mode = false;
        if (leader) {
          wbl2_wait();              // flush dirty wg-stores (no resurrection)
          st_agent_u64(s0p, pubA);  // re-publish both slots agent-scope
          st_agent_u64(s1p, pubB);
        }
      }
    }
  }
}

// ---- wave64 DPP reductions (VALU-only) -------------------------------------
template <int CTRL>
static __device__ __forceinline__ float dpp_mov(float x, float old) {
  return __int_as_float(__builtin_amdgcn_update_dpp(
      __float_as_int(old), __float_as_int(x), CTRL, 0xF, 0xF, false));
}
static __device__ __forceinline__ float half_red_sum(float x) {
  x += dpp_mov<0x111>(x, 0.0f);
  x += dpp_mov<0x112>(x, 0.0f);
  x += dpp_mov<0x114>(x, 0.0f);
  x += dpp_mov<0x118>(x, 0.0f);
  x += dpp_mov<0x142>(x, 0.0f);   // row_bcast:15
  return x;                       // lanes 31/63 hold their half's total
}
static __device__ __forceinline__ float wave_red_max63(float x) {
  const float NI = -3.0e38f;
  x = fmaxf(x, dpp_mov<0x111>(x, NI));
  x = fmaxf(x, dpp_mov<0x112>(x, NI));
  x = fmaxf(x, dpp_mov<0x114>(x, NI));
  x = fmaxf(x, dpp_mov<0x118>(x, NI));
  x = fmaxf(x, dpp_mov<0x142>(x, NI));
  x = fmaxf(x, dpp_mov<0x143>(x, NI));  // row_bcast:31
  return x;                             // lane 63 holds wave max
}
static __device__ __forceinline__ float wave_red_sum63(float x) {
  x += dpp_mov<0x111>(x, 0.0f);
  x += dpp_mov<0x112>(x, 0.0f);
  x += dpp_mov<0x114>(x, 0.0f);
  x += dpp_mov<0x118>(x, 0.0f);
  x += dpp_mov<0x142>(x, 0.0f);
  x += dpp_mov<0x143>(x, 0.0f);
  return x;
}

// ---- workspace init: 8 replica buffers + roster/claims/flags (replay-safe) -
__global__ void init_ws_kernel(unsigned long long* fvbuf, unsigned* ctrl,
                               int* bmax) {
  int i = blockIdx.x * blockDim.x + threadIdx.x;
  if (i < NGRP * 2 * K_TAGS) {
    int e = i & (2 * K_TAGS - 1);
    int slot = e >> 10;
    int rr = e & (K_TAGS - 1);
    unsigned long long v;
    if (slot == 0) {
      float f = (rr == START_TAG) ? 0.0f : NEGV * LOG2E;
      v = (1ull << 32) | (unsigned long long)__float_as_uint(f);
    } else {
      v = 0ull;
    }
    st_agent_u64(&fvbuf[i], v);
  }
  if (i < 32) {  // ctrl: roster[8] | claims | gflag[8] | pad
    __hip_atomic_store(&ctrl[i], 0u, __ATOMIC_RELAXED,
                       __HIP_MEMORY_SCOPE_AGENT);
  }
  if (i == 0) *bmax = 0;  // float 0.0 bits; true max is positive
}

// ---- gates: one wave per step t; t==T_STEPS computes the terminal gate -----
__global__ __launch_bounds__(256) void gate_kernel(
    const float* __restrict__ reps, const float* __restrict__ wc,
    const float* __restrict__ wu, const int* __restrict__ spk,
    float* __restrict__ gate, float* __restrict__ g_term) {
  const int gw = (int)((blockIdx.x * blockDim.x + threadIdx.x) >> 6);
  const int lane = threadIdx.x & 63;
  if (gw > T_STEPS) return;
  const int tcur = (gw < T_STEPS) ? gw : (T_STEPS - 1);
  const int tprv = (gw < T_STEPS) ? (gw > 0 ? gw - 1 : 0) : (T_STEPS - 1);
  const float* cur = reps + (size_t)tcur * D_DIM;
  const float* prv = reps + (size_t)tprv * D_DIM;
  float sc = 0.f, su = 0.f;
#pragma unroll
  for (int c = 0; c < 4; ++c) {
    const int d = lane * 4 + c * 256;
    float4 rp = *(const float4*)(prv + d);
    float4 rc = *(const float4*)(cur + d);
    float4 w1 = *(const float4*)(wc + d);
    float4 w2 = *(const float4*)(wc + D_DIM + d);
    float4 w3 = *(const float4*)(wu + d);
    float4 w4 = *(const float4*)(wu + D_DIM + d);
    sc += rp.x * w1.x + rp.y * w1.y + rp.z * w1.z + rp.w * w1.w;
    sc += rc.x * w2.x + rc.y * w2.y + rc.z * w2.z + rc.w * w2.w;
    su += rp.x * w3.x + rp.y * w3.y + rp.z * w3.z + rp.w * w3.w;
    su += rc.x * w4.x + rc.y * w4.y + rc.z * w4.z + rc.w * w4.w;
  }
#pragma unroll
  for (int off = 32; off; off >>= 1) {
    sc += __shfl_xor(sc, off);
    su += __shfl_xor(su, off);
  }
  if (lane == 0) {
    if (gw < T_STEPS) {
      bool uc = (gw > 0) && (spk[gw] != 0);
      float x = uc ? sc : su;
      gate[gw] = 1.0f / (1.0f + __expf(-x));
    } else {
      *g_term = 1.0f / (1.0f + __expf(-su));
    }
  }
}

// ---- global max over elementwise max(ti, ta) (for the lagged LSE shift) ----
__global__ __launch_bounds__(256) void bmax_kernel(
    const float* __restrict__ ti, const float* __restrict__ ta, int* bmax) {
  size_t i = (size_t)blockIdx.x * blockDim.x + threadIdx.x;
  size_t n = (size_t)K_TAGS * K_TAGS;
  float m = 0.f;  // clamped at 0 so int-compare atomicMax is valid
  for (size_t j = i; j < n; j += (size_t)gridDim.x * blockDim.x)
    m = fmaxf(m, fmaxf(ti[j], ta[j]));
#pragma unroll
  for (int off = 32; off; off >>= 1) m = fmaxf(m, __shfl_xor(m, off));
  if ((threadIdx.x & 63) == 0) atomicMax(bmax, __float_as_int(m));
}

// ---- persistent CRF forward scan: XCD replicas keyed by HW XCC_ID ----------
// 256 candidates read their real XCC_ID (s_getreg hwreg(20)) and claim a rank
// in that XCD's roster. First 32 per viable XCD (roster>=32) become workers;
// everyone else exits. >=1 group always viable (8*31<256). Each viable group
// independently runs the full scan through ITS XCD L2 (wg-store + sc0 load);
// all viable groups write bitwise-identical out[0].
__global__ __launch_bounds__(NTHR, 4) void crf_kernel(
    const float* __restrict__ feats, const float* __restrict__ ti,
    const float* __restrict__ ta, const float* __restrict__ gate,
    const float* __restrict__ g_term_p, const int* __restrict__ bmax_p,
    unsigned long long* fvbuf, unsigned* ctrl, float* __restrict__ out) {
  const int tid = threadIdx.x;
  const int lane = tid & 63;
  const int w = tid >> 6;                 // wave id (0..15)
  const int j = lane & 31;                // team lane within half-wave
  const int h = lane >> 5;                // half id
  const bool leader = (j == 31);          // lanes 31 and 63

  unsigned* roster = ctrl;        // [8]
  unsigned* claims = ctrl + 8;    // [1]
  unsigned* gflags = ctrl + 9;    // [8]

  // ---- roster phase: measure placement, claim a rank ----
  __shared__ int sGrp, sRank, sViable;
  if (tid == 0) {
    unsigned xcc;
    asm volatile("s_getreg_b32 %0, hwreg(20, 0, 32)" : "=s"(xcc));
    int g = (int)(xcc & 7u);
    int rk = (int)__hip_atomic_fetch_add(&roster[g], 1u, __ATOMIC_RELAXED,
                                         __HIP_MEMORY_SCOPE_AGENT);
    __hip_atomic_fetch_add(claims, 1u, __ATOMIC_RELEASE,
                           __HIP_MEMORY_SCOPE_AGENT);
    unsigned c;
    do {
      c = __hip_atomic_load(claims, __ATOMIC_ACQUIRE,
                            __HIP_MEMORY_SCOPE_AGENT);
      if (c < (unsigned)NCAND) __builtin_amdgcn_s_sleep(8);
    } while (c < (unsigned)NCAND);
    unsigned rs = __hip_atomic_load(&roster[g], __ATOMIC_RELAXED,
                                    __HIP_MEMORY_SCOPE_AGENT);
    sGrp = g;
    sRank = rk;
    sViable = (rs >= (unsigned)BPG) ? 1 : 0;
  }
  __syncthreads();
  const int grp = sGrp;
  const int rank = sRank;
  if (!sViable || rank >= BPG) return;   // surplus / defunct group: exit

  const int r = rank * ROWS_PB + 2 * w + h;  // this half-wave's row
  unsigned long long* fvg = fvbuf + (size_t)grp * (2 * K_TAGS);
  unsigned long long* myS0 = &fvg[r];
  unsigned long long* myS1 = &fvg[K_TAGS + r];
  unsigned* gflag = &gflags[grp];
  bool l2mode = true;

  __shared__ __align__(16) float fvs[2][K_TAGS];
  __shared__ __align__(16) float wredM[2][16];
  __shared__ float wredS[16];

  // register-resident, log2-scaled matrix slice: 32 cells for row r
  float ta2[32], df2[32];
  {
    const float2* taP = reinterpret_cast<const float2*>(ta + (size_t)r * K_TAGS) + j;
    const float2* tiP = reinterpret_cast<const float2*>(ti + (size_t)r * K_TAGS) + j;
#pragma unroll
    for (int c = 0; c < 16; ++c) {
      float2 a = taP[32 * c];
      float2 i_ = tiP[32 * c];
      ta2[2 * c] = a.x * LOG2E;
      df2[2 * c] = (i_.x - a.x) * LOG2E;
      ta2[2 * c + 1] = a.y * LOG2E;
      df2[2 * c + 1] = (i_.y - a.y) * LOG2E;
    }
  }
  const float bmax2 = __int_as_float(*bmax_p) * LOG2E;

  // leaders track their row's last published atoms (for fallback re-publish)
  unsigned long long pubA, pubB;
  {
    float f0 = (r == START_TAG) ? 0.0f : NEGV * LOG2E;
    pubA = (1ull << 32) | (unsigned long long)__float_as_uint(f0);
    pubB = 0ull;
  }

  if (tid < 32) wredM[tid >> 4][tid & 15] = 0.0f;  // max(fv_0)=0 for t=0
  __syncthreads();

  float featv = leader ? feats[r] : 0.0f;  // feats[0][r]

  for (int t = 0; t < T_STEPS; ++t) {
    const int slot = t & 1;
    const unsigned want = (unsigned)(t + 1);
    const float g = gate[t];

    // 1) poll own tagged entry through the group's XCD L2 (flag-coord fallback)
    unsigned long long u = poll_entry(&fvg[slot * K_TAGS + tid], want, l2mode,
                                      gflag, leader, myS0, myS1, pubA, pubB);
    const float v = __uint_as_float((unsigned)u);

    // 2) stash -> one barrier
    fvs[slot][tid] = v;
    __syncthreads();

    float featv_next = 0.0f;
    if (leader && t + 1 < T_STEPS)
      featv_next = feats[(size_t)(t + 1) * K_TAGS + r];

    // 3) lagged shift: blockmax(fv_{t-1}) + bmax2 + margin (exact; r4-proven)
    const float4 mA = *reinterpret_cast<const float4*>(&wredM[slot ^ 1][0]);
    const float4 mB = *reinterpret_cast<const float4*>(&wredM[slot ^ 1][4]);
    const float4 mC = *reinterpret_cast<const float4*>(&wredM[slot ^ 1][8]);
    const float4 mD = *reinterpret_cast<const float4*>(&wredM[slot ^ 1][12]);
    float mm = fmaxf(fmaxf(fmaxf(mA.x, mA.y), fmaxf(mA.z, mA.w)),
                     fmaxf(fmaxf(mB.x, mB.y), fmaxf(mB.z, mB.w)));
    mm = fmaxf(mm, fmaxf(fmaxf(fmaxf(mC.x, mC.y), fmaxf(mC.z, mC.w)),
                         fmaxf(fmaxf(mD.x, mD.y), fmaxf(mD.z, mD.w))));
    const float sh = mm + bmax2 + MARGIN2;

    // 4) 32 cells: acc += 2^(ta2 + g*df2 + fv - sh)
    float a0 = 0.f, a1 = 0.f;
    const float2* fp = reinterpret_cast<const float2*>(&fvs[slot][0]) + j;
#pragma unroll
    for (int c = 0; c < 16; ++c) {
      float2 f = fp[32 * c];
      a0 += exp2f(__builtin_fmaf(g, df2[2 * c], ta2[2 * c]) + (f.x - sh));
      a1 += exp2f(__builtin_fmaf(g, df2[2 * c + 1], ta2[2 * c + 1]) + (f.y - sh));
    }
    float acc = half_red_sum(a0 + a1);  // lanes 31/63 hold row sums

    // 5) leaders publish (tag t+2) via the active path
    if (leader) {
      float fvnew = sh + __log2f(acc) + featv * LOG2E;  // -inf if acc==0: OK
      unsigned long long newu =
          ((unsigned long long)(unsigned)(t + 2) << 32) |
          (unsigned long long)__float_as_uint(fvnew);
      unsigned long long* tp = (slot ^ 1) ? myS1 : myS0;
      if (l2mode) st_l2_u64(tp, newu);
      else st_agent_u64(tp, newu);
      if (slot ^ 1) pubB = newu; else pubA = newu;
    }

    // 6) off critical path: wave max of polled fv_t -> wredM[slot] for t+1
    float lm = wave_red_max63(v);
    if (lane == 63) wredM[slot][w] = lm;

    featv = featv_next;
  }

  // ---- terminal LSE: rank-31 block of EVERY viable group (identical out) ----
  if (rank == BPG - 1) {
    __syncthreads();
    const unsigned want = (unsigned)(T_STEPS + 1);
    unsigned long long u =
        poll_entry(&fvg[(T_STEPS & 1) * K_TAGS + tid], want, l2mode, gflag,
                   leader, myS0, myS1, pubA, pubB);
    const float gt = *g_term_p;
    const float tis = ti[(size_t)STOP_TAG * K_TAGS + tid];
    const float tas = ta[(size_t)STOP_TAG * K_TAGS + tid];
    const float term2 =
        __uint_as_float((unsigned)u) + (tas + gt * (tis - tas)) * LOG2E;

    float m = wave_red_max63(term2);
    if (lane == 63) wredM[0][w] = m;
    __syncthreads();
    float mm = wredM[0][0];
#pragma unroll
    for (int i = 1; i < 16; ++i) mm = fmaxf(mm, wredM[0][i]);
    float e = exp2f(term2 - mm);
    e = wave_red_sum63(e);
    if (lane == 63) wredS[w] = e;
    __syncthreads();
    if (tid == 0) {
      float s = 0.f;
#pragma unroll
      for (int i = 0; i < 16; ++i) s += wredS[i];
      out[0] = (mm + __log2f(s)) * LN2;  // identical across viable groups
    }
  }
}

extern "C" void kernel_launch(void* const* d_in, const int* in_sizes, int n_in,
                              void* d_out, int out_size, void* d_ws, size_t ws_size,
                              hipStream_t stream) {
  (void)in_sizes; (void)n_in; (void)out_size; (void)ws_size;
  const float* feats = (const float*)d_in[0];
  const float* reps  = (const float*)d_in[1];
  const float* wc    = (const float*)d_in[2];
  const float* wu    = (const float*)d_in[3];
  const float* ti    = (const float*)d_in[4];
  const float* ta    = (const float*)d_in[5];
  const int*   spk   = (const int*)d_in[6];
  float* out = (float*)d_out;

  // ws: fvbuf[8][2][1024] u64 (128 KiB) | gate[8192] f32 | g_term | bmax
  //     | ctrl[32] u32 (roster[8], claims, gflag[8], pad)
  unsigned long long* fvbuf = (unsigned long long*)d_ws;
  float* gate  = (float*)((char*)d_ws +
                          (size_t)NGRP * 2 * K_TAGS * sizeof(unsigned long long));
  float* gterm = gate + T_STEPS;
  int*   bmax  = (int*)(gterm + 1);
  unsigned* ctrl = (unsigned*)(bmax + 1);

  init_ws_kernel<<<dim3(64), dim3(256), 0, stream>>>(fvbuf, ctrl, bmax);
  gate_kernel<<<dim3((T_STEPS + 1 + 3) / 4), dim3(256), 0, stream>>>(
      reps, wc, wu, spk, gate, gterm);
  bmax_kernel<<<dim3(512), dim3(256), 0, stream>>>(ti, ta, bmax);
  crf_kernel<<<dim3(NCAND), dim3(NTHR), 0, stream>>>(feats, ti, ta, gate, gterm,
                                                     bmax, fvbuf, ctrl, out);
}